// Round 3
// baseline (97.873 us; speedup 1.0000x reference)
//
#include <hip/hip_runtime.h>

#define N 512
#define D 512
#define TILE 32
#define DC 64          // d-slice per block
#define PITCH 68       // LDS pitch (floats): 68 % 32 = 4 -> at most 2-way conflict (free); 16B-aligned
#define NT 16          // N/TILE
#define NTILES 136     // NT*(NT+1)/2 upper-triangular tiles
#define NSLICE 8       // D/DC

__device__ __forceinline__ void sl1(float& acc, float x, float y) {
    // 2*SmoothL1(d) = m*(2|d|-m), m=min(|d|,1); the 0.5 is applied in the epilogue
    float d  = x - y;
    float ad = fabsf(d);
    float m  = fminf(ad, 1.0f);
    acc = fmaf(m, fmaf(2.0f, ad, -m), acc);
}

// Ppart layout: [2 mats][NSLICE][N*N] f32 partial pair-sums = 16 MB in d_ws.
// Only upper-triangular (i<=j) entries are written; final_kernel masks the rest.

__global__ __launch_bounds__(256, 8) void pair_sums_kernel(
    const float* __restrict__ Tm, const float* __restrict__ Sm,
    float* __restrict__ Pp, float* __restrict__ sums)
{
    // grid: x = NTILES (upper-tri tile id), y = slice, z = mat
    const int mat = blockIdx.z;
    const int sl  = blockIdx.y;
    const float* __restrict__ X = mat ? Sm : Tm;
    float* __restrict__ Pm = Pp + (size_t)(mat * NSLICE + sl) * (N * N);

    // decode triangular tile index -> (ti, tj), ti <= tj (uniform scalar loop)
    int rem = blockIdx.x, ti = 0;
    while (rem >= NT - ti) { rem -= NT - ti; ++ti; }
    const int tj = ti + rem;
    const int i0 = ti * TILE, j0 = tj * TILE;
    const int d0 = sl * DC;

    __shared__ float Xi[TILE][PITCH];
    __shared__ float Xj[TILE][PITCH];

    const int t  = threadIdx.x;
    const int tx = t & 15;
    const int ty = t >> 4;

    // stage the 32x64 chunks (512 float4 per array, 2 per thread per array)
    #pragma unroll
    for (int kk = 0; kk < 2; ++kk) {
        int idx = t + kk * 256;
        int row = idx >> 4;            // 16 float4 per row
        int c4  = (idx & 15) * 4;
        *(float4*)&Xi[row][c4] = *(const float4*)&X[(size_t)(i0 + row) * D + d0 + c4];
        *(float4*)&Xj[row][c4] = *(const float4*)&X[(size_t)(j0 + row) * D + d0 + c4];
    }
    __syncthreads();   // the only barrier before the reduction epilogue

    float a00 = 0.f, a01 = 0.f, a10 = 0.f, a11 = 0.f;
    #pragma unroll 4
    for (int d4 = 0; d4 < DC / 4; ++d4) {
        float4 p0 = *(const float4*)&Xi[ty][d4 * 4];
        float4 p1 = *(const float4*)&Xi[ty + 16][d4 * 4];
        float4 q0 = *(const float4*)&Xj[tx][d4 * 4];
        float4 q1 = *(const float4*)&Xj[tx + 16][d4 * 4];
        sl1(a00, p0.x, q0.x); sl1(a00, p0.y, q0.y); sl1(a00, p0.z, q0.z); sl1(a00, p0.w, q0.w);
        sl1(a01, p0.x, q1.x); sl1(a01, p0.y, q1.y); sl1(a01, p0.z, q1.z); sl1(a01, p0.w, q1.w);
        sl1(a10, p1.x, q0.x); sl1(a10, p1.y, q0.y); sl1(a10, p1.z, q0.z); sl1(a10, p1.w, q0.w);
        sl1(a11, p1.x, q1.x); sl1(a11, p1.y, q1.y); sl1(a11, p1.z, q1.z); sl1(a11, p1.w, q1.w);
    }

    // masks: only store pairs with global i <= j
    const bool diag = (ti == tj);
    const bool w00 = !diag || (ty <= tx);   // (ty, tx) and (ty+16, tx+16)
    const bool w10 = !diag;                 // (ty+16, tx): on diag never i<=j
    // (ty, tx+16): on diag ty<=15<16<=tx+16 -> always i<j, always stored
    const float s00 = 0.5f * a00, s01 = 0.5f * a01, s10 = 0.5f * a10, s11 = 0.5f * a11;

    float bs = 0.f;
    if (w00) { Pm[(i0 + ty     ) * N + (j0 + tx     )] = s00; bs += s00; }
              { Pm[(i0 + ty     ) * N + (j0 + tx + 16)] = s01; bs += s01; }
    if (w10) { Pm[(i0 + ty + 16) * N + (j0 + tx     )] = s10; bs += s10; }
    if (w00) { Pm[(i0 + ty + 16) * N + (j0 + tx + 16)] = s11; bs += s11; }

    // block sum -> ONE global atomic per block (2176 total, negligible)
    #pragma unroll
    for (int off = 32; off > 0; off >>= 1) bs += __shfl_down(bs, off, 64);
    __shared__ float wpart[4];
    if ((t & 63) == 0) wpart[t >> 6] = bs;
    __syncthreads();
    if (t == 0) atomicAdd(&sums[mat], wpart[0] + wpart[1] + wpart[2] + wpart[3]);
}

__global__ __launch_bounds__(256) void final_kernel(
    const float* __restrict__ Pp, const float* __restrict__ sums, float* __restrict__ out)
{
    const float NN = (float)N * (float)N;
    const float cT = NN / (2.0f * sums[0]);   // 1/mean_T: mean over N^2 = 2*Sum_{i<j}/N^2
    const float cS = NN / (2.0f * sums[1]);
    float local = 0.0f;
    const int nvec = N * N / 4;
    for (int v = blockIdx.x * 256 + threadIdx.x; v < nvec; v += gridDim.x * 256) {
        int i  = v >> 7;            // (v*4) / 512
        int jb = (v & 127) * 4;     // (v*4) % 512
        if (jb + 3 < i) continue;   // vector fully below diagonal: never written
        float4 tq = make_float4(0.f, 0.f, 0.f, 0.f);
        float4 sq = make_float4(0.f, 0.f, 0.f, 0.f);
        #pragma unroll
        for (int s = 0; s < NSLICE; ++s) {
            float4 a = ((const float4*)(Pp + (size_t)s * (N * N)))[v];
            float4 b = ((const float4*)(Pp + (size_t)(NSLICE + s) * (N * N)))[v];
            tq.x += a.x; tq.y += a.y; tq.z += a.z; tq.w += a.w;
            sq.x += b.x; sq.y += b.y; sq.z += b.z; sq.w += b.w;
        }
        // exact per-element mask excludes unwritten (poisoned) below-diagonal slots
        if (jb + 0 >= i) local += fabsf(tq.x * cT - sq.x * cS);
        if (jb + 1 >= i) local += fabsf(tq.y * cT - sq.y * cS);
        if (jb + 2 >= i) local += fabsf(tq.z * cT - sq.z * cS);
        if (jb + 3 >= i) local += fabsf(tq.w * cT - sq.w * cS);
    }
    #pragma unroll
    for (int off = 32; off > 0; off >>= 1) local += __shfl_down(local, off, 64);
    __shared__ float wpart[4];
    if ((threadIdx.x & 63) == 0) wpart[threadIdx.x >> 6] = local;
    __syncthreads();
    if (threadIdx.x == 0) atomicAdd(out, 2.0f * (wpart[0] + wpart[1] + wpart[2] + wpart[3]));
}

extern "C" void kernel_launch(void* const* d_in, const int* in_sizes, int n_in,
                              void* d_out, int out_size, void* d_ws, size_t ws_size,
                              hipStream_t stream) {
    const float* teacher = (const float*)d_in[0];
    const float* student = (const float*)d_in[1];
    float* out  = (float*)d_out;
    float* Pp   = (float*)d_ws;                             // [2][NSLICE][N*N] = 16 MB
    float* sums = Pp + (size_t)2 * NSLICE * N * N;          // [2] global sums

    // zero only the atomically-accumulated scalars (P holes are masked, not zeroed)
    hipMemsetAsync(sums, 0, 2 * sizeof(float), stream);
    hipMemsetAsync(d_out, 0, sizeof(float), stream);

    dim3 grid(NTILES, NSLICE, 2);
    pair_sums_kernel<<<grid, 256, 0, stream>>>(teacher, student, Pp, sums);
    final_kernel<<<256, 256, 0, stream>>>(Pp, sums, out);
}

// Round 4
// 85.027 us; speedup vs baseline: 1.1511x; 1.1511x over previous
//
#include <hip/hip_runtime.h>

#define N 512
#define D 512
#define TILE 32
#define DC 64          // d-chunk staged in LDS at a time
#define PITCH 68       // LDS pitch: 68%32=4 -> worst 2-way bank alias (free); 16B aligned
#define NT 16          // N/TILE
#define NTILES 136     // upper-triangular tiles
#define NSLICE 4       // partial slabs per matrix
#define CHUNKS 2       // d-chunks per block; each slice covers CHUNKS*DC = 128 dims

__device__ __forceinline__ void sl1(float& acc, float x, float y) {
    // 2*SmoothL1(d) = m*(2|d|-m), m=min(|d|,1); 0.5 applied in epilogue
    float d  = x - y;
    float ad = fabsf(d);
    float m  = fminf(ad, 1.0f);
    acc = fmaf(m, fmaf(2.0f, ad, -m), acc);
}

// Pp layout: [2 mats][NSLICE][N*N] f32 partial pair-sums = 8 MB in d_ws.
// Full tiles are stored (below-diagonal values are garbage-but-written);
// final_kernel applies the exact i<=j mask, so no zeroing of Pp is needed.

__global__ __launch_bounds__(256, 8) void pair_sums_kernel(
    const float* __restrict__ Tm, const float* __restrict__ Sm,
    float* __restrict__ Pp, float* __restrict__ sums)
{
    // grid: x = NTILES (upper-tri tile id), y = slice, z = mat
    const int mat = blockIdx.z;
    const int sl  = blockIdx.y;
    const float* __restrict__ X = mat ? Sm : Tm;
    float* __restrict__ Pm = Pp + (size_t)(mat * NSLICE + sl) * (N * N);

    // triangular tile decode -> (ti, tj), ti <= tj
    int rem = blockIdx.x, ti = 0;
    while (rem >= NT - ti) { rem -= NT - ti; ++ti; }
    const int tj = ti + rem;
    const int i0 = ti * TILE, j0 = tj * TILE;

    __shared__ float Xi[TILE][PITCH];
    __shared__ float Xj[TILE][PITCH];

    const int t  = threadIdx.x;
    const int tx = t & 15;
    const int ty = t >> 4;

    float a00 = 0.f, a01 = 0.f, a10 = 0.f, a11 = 0.f;

    for (int c = 0; c < CHUNKS; ++c) {
        const int d0 = (sl * CHUNKS + c) * DC;
        if (c) __syncthreads();          // protect LDS from previous chunk's readers
        #pragma unroll
        for (int kk = 0; kk < 2; ++kk) {
            int idx = t + kk * 256;      // 512 float4 per array, 2 per thread
            int row = idx >> 4;
            int c4  = (idx & 15) * 4;
            *(float4*)&Xi[row][c4] = *(const float4*)&X[(size_t)(i0 + row) * D + d0 + c4];
            *(float4*)&Xj[row][c4] = *(const float4*)&X[(size_t)(j0 + row) * D + d0 + c4];
        }
        __syncthreads();
        #pragma unroll
        for (int d4 = 0; d4 < DC / 4; ++d4) {
            float4 p0 = *(const float4*)&Xi[ty][d4 * 4];
            float4 p1 = *(const float4*)&Xi[ty + 16][d4 * 4];
            float4 q0 = *(const float4*)&Xj[tx][d4 * 4];
            float4 q1 = *(const float4*)&Xj[tx + 16][d4 * 4];
            sl1(a00, p0.x, q0.x); sl1(a00, p0.y, q0.y); sl1(a00, p0.z, q0.z); sl1(a00, p0.w, q0.w);
            sl1(a01, p0.x, q1.x); sl1(a01, p0.y, q1.y); sl1(a01, p0.z, q1.z); sl1(a01, p0.w, q1.w);
            sl1(a10, p1.x, q0.x); sl1(a10, p1.y, q0.y); sl1(a10, p1.z, q0.z); sl1(a10, p1.w, q0.w);
            sl1(a11, p1.x, q1.x); sl1(a11, p1.y, q1.y); sl1(a11, p1.z, q1.z); sl1(a11, p1.w, q1.w);
        }
    }

    const float s00 = 0.5f * a00, s01 = 0.5f * a01, s10 = 0.5f * a10, s11 = 0.5f * a11;

    // unconditional full-tile stores (no divergence); mask only the scalar sum
    Pm[(i0 + ty     ) * N + (j0 + tx     )] = s00;
    Pm[(i0 + ty     ) * N + (j0 + tx + 16)] = s01;
    Pm[(i0 + ty + 16) * N + (j0 + tx     )] = s10;
    Pm[(i0 + ty + 16) * N + (j0 + tx + 16)] = s11;

    float bs;
    if (ti == tj) {
        // keep only global i<=j: (ty,tx) iff ty<=tx; (ty,tx+16) always; (ty+16,tx) never; (ty+16,tx+16) iff ty<=tx
        bs = (ty <= tx ? s00 + s11 : 0.f) + s01;
    } else {
        bs = s00 + s01 + s10 + s11;
    }

    #pragma unroll
    for (int off = 32; off > 0; off >>= 1) bs += __shfl_down(bs, off, 64);
    __shared__ float wpart[4];
    if ((t & 63) == 0) wpart[t >> 6] = bs;
    __syncthreads();
    if (t == 0) atomicAdd(&sums[mat], wpart[0] + wpart[1] + wpart[2] + wpart[3]);
}

__global__ __launch_bounds__(256) void final_kernel(
    const float* __restrict__ Pp, const float* __restrict__ sums, float* __restrict__ out)
{
    const float NN = (float)N * (float)N;
    const float cT = NN / (2.0f * sums[0]);   // 1/mean_T (full-matrix mean = 2*Sum_{i<j}/N^2)
    const float cS = NN / (2.0f * sums[1]);

    const int v  = blockIdx.x * 256 + threadIdx.x;   // exactly N*N/4 = 65536 threads
    const int i  = v >> 7;            // (v*4) / 512
    const int jb = (v & 127) * 4;     // (v*4) % 512

    float local = 0.0f;
    if (jb + 3 >= i) {                // skip float4s entirely below the diagonal
        float4 tq = make_float4(0.f, 0.f, 0.f, 0.f);
        float4 sq = make_float4(0.f, 0.f, 0.f, 0.f);
        #pragma unroll
        for (int s = 0; s < NSLICE; ++s) {
            float4 a = ((const float4*)(Pp + (size_t)s * (N * N)))[v];
            float4 b = ((const float4*)(Pp + (size_t)(NSLICE + s) * (N * N)))[v];
            tq.x += a.x; tq.y += a.y; tq.z += a.z; tq.w += a.w;
            sq.x += b.x; sq.y += b.y; sq.z += b.z; sq.w += b.w;
        }
        if (jb + 0 >= i) local += fabsf(tq.x * cT - sq.x * cS);
        if (jb + 1 >= i) local += fabsf(tq.y * cT - sq.y * cS);
        if (jb + 2 >= i) local += fabsf(tq.z * cT - sq.z * cS);
        if (jb + 3 >= i) local += fabsf(tq.w * cT - sq.w * cS);
    }

    #pragma unroll
    for (int off = 32; off > 0; off >>= 1) local += __shfl_down(local, off, 64);
    __shared__ float wpart[4];
    if ((threadIdx.x & 63) == 0) wpart[threadIdx.x >> 6] = local;
    __syncthreads();
    if (threadIdx.x == 0) atomicAdd(out, 2.0f * (wpart[0] + wpart[1] + wpart[2] + wpart[3]));
}

extern "C" void kernel_launch(void* const* d_in, const int* in_sizes, int n_in,
                              void* d_out, int out_size, void* d_ws, size_t ws_size,
                              hipStream_t stream) {
    const float* teacher = (const float*)d_in[0];
    const float* student = (const float*)d_in[1];
    float* out  = (float*)d_out;
    float* Pp   = (float*)d_ws;                             // [2][NSLICE][N*N] = 8 MB
    float* sums = Pp + (size_t)2 * NSLICE * N * N;          // [2] global sums

    hipMemsetAsync(sums, 0, 2 * sizeof(float), stream);
    hipMemsetAsync(d_out, 0, sizeof(float), stream);

    dim3 grid(NTILES, NSLICE, 2);
    pair_sums_kernel<<<grid, 256, 0, stream>>>(teacher, student, Pp, sums);
    final_kernel<<<N * N / 4 / 256, 256, 0, stream>>>(Pp, sums, out);
}